// Round 13
// baseline (81.606 us; speedup 1.0000x reference)
//
#include <hip/hip_runtime.h>
#include <hip/hip_bf16.h>
#include <stdint.h>

typedef __bf16 bf16;
typedef __bf16 bf16x8 __attribute__((ext_vector_type(8)));
typedef __bf16 bf16x4 __attribute__((ext_vector_type(4)));
typedef float f32x4 __attribute__((ext_vector_type(4)));

template <int V> struct Int { static constexpr int value = V; };

// async global->LDS, 16B per lane. LDS dest must be linear in lane order.
static __device__ __forceinline__ void gl2lds16(const void* g, void* l) {
  const __attribute__((address_space(1))) void* gp =
      reinterpret_cast<const __attribute__((address_space(1))) void*>(
          reinterpret_cast<uintptr_t>(g));
  __attribute__((address_space(3))) void* lp =
      reinterpret_cast<__attribute__((address_space(3))) void*>(
          static_cast<uint32_t>(reinterpret_cast<uintptr_t>(l)));
  __builtin_amdgcn_global_load_lds(gp, lp, 16, 0, 0);
}

// bare v_exp_f32 through the compiler intrinsic (hazard-safe, unlike inline asm).
static __device__ __forceinline__ float fast_exp2(float x) {
#if __has_builtin(__builtin_amdgcn_exp2f)
  return __builtin_amdgcn_exp2f(x);
#else
  return exp2f(x);
#endif
}

// One fused convert: x (4,194,304 f32) | w_qkv (786,432) | w_out (262,144) ->
// contiguous bf16 stream in ws (xb|wqkvb|woutb are adjacent).
__global__ __launch_bounds__(256) void cvt_all(const float* __restrict__ x,
                                               const float* __restrict__ wq,
                                               const float* __restrict__ wo,
                                               bf16* __restrict__ dst) {
  int i = blockIdx.x * 256 + threadIdx.x;
  const int stride = gridDim.x * 256;
  for (; i < 1310720; i += stride) {
    const float4 v = (i < 1048576) ? reinterpret_cast<const float4*>(x)[i]
                   : (i < 1245184) ? reinterpret_cast<const float4*>(wq)[i - 1048576]
                                   : reinterpret_cast<const float4*>(wo)[i - 1245184];
    bf16x4 o;
    o[0] = (bf16)v.x; o[1] = (bf16)v.y; o[2] = (bf16)v.z; o[3] = (bf16)v.w;
    reinterpret_cast<bf16x4*>(dst)[i] = o;
  }
}

// C[m][e] = sum_k X[m][k] * W[e][k];  M=8192, N=1536, K=512.  128x128 tile, BK=32.
// 4 waves, each owns 64x64 (4x4 frags of 16x16x32). Epilogue scatters Q/K/V^T.
__global__ __launch_bounds__(256) void qkv_gemm(const bf16* __restrict__ X,
                                                const bf16* __restrict__ W,
                                                bf16* __restrict__ Qb,
                                                bf16* __restrict__ Kb,
                                                bf16* __restrict__ Vt) {
  __shared__ __align__(16) bf16 AshX[8192];  // [2][128*32]
  __shared__ __align__(16) bf16 BshX[8192];
  const int t = threadIdx.x;
  const int lane = t & 63;
  const int w = t >> 6;
  const int fr = lane & 15, fg = lane >> 4;
  const int wr = w >> 1, wc = w & 1;
  const int m0 = blockIdx.x * 128;
  const int n0 = blockIdx.y * 128;
  // staging: chunk t -> row t>>2, seg t&3 -> LDS elem t*8; chunk t+256 -> +2048
  const int r0 = t >> 2, seg = t & 3;
  const bf16* pA0 = X + (m0 + r0) * 512 + seg * 8;
  const bf16* pA1 = X + (m0 + r0 + 64) * 512 + seg * 8;
  const bf16* pB0 = W + (n0 + r0) * 512 + seg * 8;
  const bf16* pB1 = W + (n0 + r0 + 64) * 512 + seg * 8;
  const bf16* ap = AshX + (wr * 64 + fr) * 32 + fg * 8;
  const bf16* bp = BshX + (wc * 64 + fr) * 32 + fg * 8;

  f32x4 acc[4][4] = {};

  auto stage = [&](auto Bt) {
    constexpr int B = decltype(Bt)::value;
    gl2lds16(pA0, (void*)(AshX + B * 4096 + t * 8));
    gl2lds16(pA1, (void*)(AshX + B * 4096 + 2048 + t * 8));
    gl2lds16(pB0, (void*)(BshX + B * 4096 + t * 8));
    gl2lds16(pB1, (void*)(BshX + B * 4096 + 2048 + t * 8));
    pA0 += 32; pA1 += 32; pB0 += 32; pB1 += 32;
  };
  auto step = [&](auto Bt) {
    constexpr int B = decltype(Bt)::value;
    bf16x8 a[4], b[4];
#pragma unroll
    for (int m = 0; m < 4; ++m) a[m] = *reinterpret_cast<const bf16x8*>(ap + B * 4096 + m * 512);
#pragma unroll
    for (int n = 0; n < 4; ++n) b[n] = *reinterpret_cast<const bf16x8*>(bp + B * 4096 + n * 512);
#pragma unroll
    for (int m = 0; m < 4; ++m)
#pragma unroll
      for (int n = 0; n < 4; ++n)
        acc[m][n] = __builtin_amdgcn_mfma_f32_16x16x32_bf16(a[m], b[n], acc[m][n], 0, 0, 0);
  };

  stage(Int<0>{});
  __syncthreads();
  for (int kt = 0; kt < 16; kt += 2) {
    stage(Int<1>{});
    step(Int<0>{});
    __syncthreads();
    if (kt < 14) stage(Int<0>{});
    step(Int<1>{});
    __syncthreads();
  }

  // epilogue. C/D: col = lane&15 -> e = n0+wc*64+16n+fr; row = m0+wr*64+16m+fg*4+r
  const int which = n0 >> 9;  // 0=Q 1=K 2=V (uniform per block)
#pragma unroll
  for (int n = 0; n < 4; ++n) {
    const int e = n0 + wc * 64 + 16 * n + fr;
    const int h = (e >> 6) & 7;
    const int d = e & 63;
#pragma unroll
    for (int m = 0; m < 4; ++m) {
      const int mbase = m0 + wr * 64 + 16 * m + fg * 4;
      if (which == 2) {
        bf16x4 pk;
#pragma unroll
        for (int r = 0; r < 4; ++r) pk[r] = (bf16)acc[m][n][r];
        const int b = mbase >> 11, tok = mbase & 2047;
        *reinterpret_cast<bf16x4*>(&Vt[((b * 8 + h) * 64 + d) * 2048 + tok]) = pk;
      } else {
        bf16* dst = (which == 0) ? Qb : Kb;
        const float sc = (which == 0) ? (0.125f * 1.44269504088896f) : 1.0f;
#pragma unroll
        for (int r = 0; r < 4; ++r) {
          const int row = mbase + r;
          const int b = row >> 11, tok = row & 2047;
          dst[((b * 8 + h) * 2048 + tok) * 64 + d] = (bf16)(acc[m][n][r] * sc);
        }
      }
    }
  }
}

// Flash attention, swapped-operand, no-max exp2 softmax, q=32 per wave,
// IN-BLOCK KV SPLIT: 512 threads = 2 wave-groups x 4 waves. Group g processes
// KV rows [g*1024, g*1024+1024) (16 tiles of 64) into its own 32KB LDS arena.
// No-max softmax => partials combine EXACTLY additively: O = O0+O1, l = l0+l1,
// reduced through LDS at the end (group1 stores, group0 adds+normalizes+writes).
// Waves/CU: 16 (4/SIMD) at 2 blocks/CU (64KB LDS) -- fixes r12's latency bind.
// Q [BH][2048][64] (prescaled by 0.125*log2e), K [BH][2048][64], V^T [BH][64][2048].
// Grid (32 bh, 16 qtile): id == bh (mod 8) -> one XCD per head (L2-resident K/V).
// K rows PERMUTED at staging so S^T lands in PV B-frag layout (see r3 header).
// Per group: 2-slot double-buffer; arena: K slot s @ bytes s*8192, V @ 16384+s*8192.
__global__ __launch_bounds__(512, 4) void attn_fwd(const bf16* __restrict__ Qb,
                                                   const bf16* __restrict__ Kb,
                                                   const bf16* __restrict__ Vt,
                                                   bf16* __restrict__ Ob) {
  __shared__ __align__(16) bf16 sh[32768];  // 2 arenas x 32KB
  const int t = threadIdx.x;
  const int lane = t & 63;
  const int w = t >> 6;       // 0..7
  const int g = w >> 2;       // KV-half group
  const int wl = w & 3;       // q-tile wave within group
  const int fr = lane & 15, fg = lane >> 4;
  const int bh = blockIdx.x;
  const int q0 = blockIdx.y * 128 + 32 * wl;

  // Q fragments (B-operand): col=q, k = 8*fg + i; sets A (q0+fr) and B (q0+16+fr)
  const bf16* Qrow = Qb + (bh * 2048 + q0 + fr) * 64;
  const bf16x8 qa0 = *reinterpret_cast<const bf16x8*>(Qrow + fg * 8);
  const bf16x8 qa1 = *reinterpret_cast<const bf16x8*>(Qrow + 32 + fg * 8);
  const bf16x8 qb0 = *reinterpret_cast<const bf16x8*>(Qrow + 1024 + fg * 8);
  const bf16x8 qb1 = *reinterpret_cast<const bf16x8*>(Qrow + 1024 + 32 + fg * 8);

  bf16x8 ones;
#pragma unroll
  for (int i = 0; i < 8; ++i) ones[i] = (bf16)1.0f;

  // staging (per group, 256 threads): chunk c: LDS row=c>>3, seg=c&7;
  // src seg ^= (dstrow&7); K row-permuted.
  const int tg = t & 255;
  const int c0row = tg >> 3, cseg = tg & 7;
  const int c1row = c0row + 32;
  const int s0 = (cseg ^ (c0row & 7)) * 8;
  const int s1 = (cseg ^ (c1row & 7)) * 8;
  const int kp0 = 32 * ((c0row >> 4) >> 1) + 8 * ((c0row & 15) >> 2) +
                  4 * ((c0row >> 4) & 1) + (c0row & 3);
  const int kp1 = 32 * ((c1row >> 4) >> 1) + 8 * ((c1row & 15) >> 2) +
                  4 * ((c1row >> 4) & 1) + (c1row & 3);
  const int kvbase = g * 1024;  // this group's KV row offset
  const bf16* pK0 = Kb + bh * 131072 + (kvbase + kp0) * 64 + s0;
  const bf16* pK1 = Kb + bh * 131072 + (kvbase + kp1) * 64 + s1;
  const bf16* pV0 = Vt + bh * 131072 + c0row * 2048 + kvbase + s0;
  const bf16* pV1 = Vt + bh * 131072 + c1row * 2048 + kvbase + s1;

  bf16* ar = sh + g * 16384;  // this group's arena (elements)
  const char* shb = reinterpret_cast<const char*>(sh) + g * 32768;  // bytes
  const int swz = (fr & 7) << 4;
  const int ko0 = fr * 128 + ((fg * 16) ^ swz);
  const int ko1 = fr * 128 + ((64 + fg * 16) ^ swz);

  f32x4 oA[4] = {}, oB[4] = {};
  f32x4 lA = {}, lB = {};
  const f32x4 fzero = {0.f, 0.f, 0.f, 0.f};

  auto stage = [&](auto St) {
    constexpr int S = decltype(St)::value;
    gl2lds16(pK0, (void*)(ar + S * 4096 + tg * 8));
    gl2lds16(pK1, (void*)(ar + S * 4096 + 2048 + tg * 8));
    gl2lds16(pV0, (void*)(ar + 8192 + S * 4096 + tg * 8));
    gl2lds16(pV1, (void*)(ar + 8192 + S * 4096 + 2048 + tg * 8));
    pK0 += 4096; pK1 += 4096; pV0 += 64; pV1 += 64;
  };

  auto compute = [&](auto St) {
    constexpr int S = decltype(St)::value;
    f32x4 sA[4], sB[4];
#pragma unroll
    for (int j = 0; j < 4; ++j) {
      const bf16x8 kf0 = *reinterpret_cast<const bf16x8*>(shb + ko0 + (S * 8192 + j * 2048));
      sA[j] = __builtin_amdgcn_mfma_f32_16x16x32_bf16(kf0, qa0, fzero, 0, 0, 0);
      sB[j] = __builtin_amdgcn_mfma_f32_16x16x32_bf16(kf0, qb0, fzero, 0, 0, 0);
      const bf16x8 kf1 = *reinterpret_cast<const bf16x8*>(shb + ko1 + (S * 8192 + j * 2048));
      sA[j] = __builtin_amdgcn_mfma_f32_16x16x32_bf16(kf1, qa1, sA[j], 0, 0, 0);
      sB[j] = __builtin_amdgcn_mfma_f32_16x16x32_bf16(kf1, qb1, sB[j], 0, 0, 0);
    }
    // half 0: exp for j=0,1 of both q-sets; PV half 0 only needs these
    bf16x8 pA0, pB0;
#pragma unroll
    for (int j = 0; j < 2; ++j)
#pragma unroll
      for (int r = 0; r < 4; ++r) {
        pA0[4 * j + r] = (bf16)fast_exp2(sA[j][r]);
        pB0[4 * j + r] = (bf16)fast_exp2(sB[j][r]);
      }
    __builtin_amdgcn_s_setprio(1);
    lA = __builtin_amdgcn_mfma_f32_16x16x32_bf16(ones, pA0, lA, 0, 0, 0);
    lB = __builtin_amdgcn_mfma_f32_16x16x32_bf16(ones, pB0, lB, 0, 0, 0);
#pragma unroll
    for (int j = 0; j < 4; ++j) {
      const bf16x8 vf = *reinterpret_cast<const bf16x8*>(
          shb + ko0 + (16384 + S * 8192 + j * 2048));
      oA[j] = __builtin_amdgcn_mfma_f32_16x16x32_bf16(vf, pA0, oA[j], 0, 0, 0);
      oB[j] = __builtin_amdgcn_mfma_f32_16x16x32_bf16(vf, pB0, oB[j], 0, 0, 0);
    }
    __builtin_amdgcn_s_setprio(0);
    // half 1
    bf16x8 pA1, pB1;
#pragma unroll
    for (int j = 2; j < 4; ++j)
#pragma unroll
      for (int r = 0; r < 4; ++r) {
        pA1[4 * (j - 2) + r] = (bf16)fast_exp2(sA[j][r]);
        pB1[4 * (j - 2) + r] = (bf16)fast_exp2(sB[j][r]);
      }
    __builtin_amdgcn_s_setprio(1);
    lA = __builtin_amdgcn_mfma_f32_16x16x32_bf16(ones, pA1, lA, 0, 0, 0);
    lB = __builtin_amdgcn_mfma_f32_16x16x32_bf16(ones, pB1, lB, 0, 0, 0);
#pragma unroll
    for (int j = 0; j < 4; ++j) {
      const bf16x8 vf = *reinterpret_cast<const bf16x8*>(
          shb + ko1 + (16384 + S * 8192 + j * 2048));
      oA[j] = __builtin_amdgcn_mfma_f32_16x16x32_bf16(vf, pA1, oA[j], 0, 0, 0);
      oB[j] = __builtin_amdgcn_mfma_f32_16x16x32_bf16(vf, pB1, oB[j], 0, 0, 0);
    }
    __builtin_amdgcn_s_setprio(0);
  };

  stage(Int<0>{});
  __syncthreads();
  for (int kt = 0; kt < 16; kt += 2) {
    stage(Int<1>{});
    compute(Int<0>{});
    __syncthreads();
    if (kt < 14) stage(Int<0>{});
    compute(Int<1>{});
    __syncthreads();
  }
  // loop ends with a barrier: all LDS reads complete -> safe to reuse for reduce.

  // cross-group reduce: group1 stores raw partials (stride 34 floats: 2-way bank
  // alias only, free), group0 adds, normalizes, writes.
  if (g == 1) {
    float* dst = reinterpret_cast<float*>(sh) + (wl * 64 + lane) * 34;
#pragma unroll
    for (int j = 0; j < 4; ++j) {
      *reinterpret_cast<f32x4*>(dst + 4 * j) = oA[j];
      *reinterpret_cast<f32x4*>(dst + 16 + 4 * j) = oB[j];
    }
    dst[32] = lA[0];
    dst[33] = lB[0];
  }
  __syncthreads();
  if (g == 0) {
    const float* src = reinterpret_cast<const float*>(sh) + (wl * 64 + lane) * 34;
#pragma unroll
    for (int j = 0; j < 4; ++j) {
      oA[j] += *reinterpret_cast<const f32x4*>(src + 4 * j);
      oB[j] += *reinterpret_cast<const f32x4*>(src + 16 + 4 * j);
    }
    const float invA = 1.0f / (lA[0] + src[32]);
    const float invB = 1.0f / (lB[0] + src[33]);
    const int b = bh >> 3, h = bh & 7;
    const int qA = q0 + fr;
#pragma unroll
    for (int j = 0; j < 4; ++j) {
      bf16x4 o4;
#pragma unroll
      for (int r = 0; r < 4; ++r) o4[r] = (bf16)(oA[j][r] * invA);
      *reinterpret_cast<bf16x4*>(&Ob[(b * 2048 + qA) * 512 + h * 64 + 16 * j + 4 * fg]) = o4;
#pragma unroll
      for (int r = 0; r < 4; ++r) o4[r] = (bf16)(oB[j][r] * invB);
      *reinterpret_cast<bf16x4*>(&Ob[(b * 2048 + qA + 16) * 512 + h * 64 + 16 * j + 4 * fg]) = o4;
    }
  }
}

// Y[m][n] = sum_k O[m][k]*W[n][k] + bias[n];  M=8192, N=512, K=512. fp32 out.
// 64x64 tile (r11-proven: 1024 blocks = 4/CU; 128^2 at 1 block/CU regressed).
__global__ __launch_bounds__(256) void out_gemm(const bf16* __restrict__ O,
                                                const bf16* __restrict__ W,
                                                const float* __restrict__ bias,
                                                float* __restrict__ Y) {
  __shared__ __align__(16) bf16 Ash[2][64 * 32];
  __shared__ __align__(16) bf16 Bsh[2][64 * 32];
  const int t = threadIdx.x;
  const int lane = t & 63;
  const int w = t >> 6;
  const int fr = lane & 15, fg = lane >> 4;
  const int m0 = blockIdx.x * 64;
  const int n0 = blockIdx.y * 64;
  const int srow = t >> 2, sseg = t & 3;
  const bf16* gA = O + (m0 + srow) * 512 + sseg * 8;
  const bf16* gB = W + (n0 + srow) * 512 + sseg * 8;

  f32x4 acc[4] = {};
  gl2lds16(gA, &Ash[0][t * 8]);
  gl2lds16(gB, &Bsh[0][t * 8]);
  __syncthreads();
  int cur = 0;
  for (int kt = 0; kt < 16; ++kt) {
    if (kt < 15) {
      gl2lds16(gA + (kt + 1) * 32, &Ash[cur ^ 1][t * 8]);
      gl2lds16(gB + (kt + 1) * 32, &Bsh[cur ^ 1][t * 8]);
    }
    const bf16x8 a = *reinterpret_cast<const bf16x8*>(&Ash[cur][(16 * w + fr) * 32 + fg * 8]);
#pragma unroll
    for (int j = 0; j < 4; ++j) {
      const bf16x8 b = *reinterpret_cast<const bf16x8*>(&Bsh[cur][(16 * j + fr) * 32 + fg * 8]);
      acc[j] = __builtin_amdgcn_mfma_f32_16x16x32_bf16(a, b, acc[j], 0, 0, 0);
    }
    __syncthreads();
    cur ^= 1;
  }
  const int mbase = m0 + 16 * w + fg * 4;
#pragma unroll
  for (int j = 0; j < 4; ++j) {
    const int col = n0 + 16 * j + fr;
    const float bv = bias[col];
#pragma unroll
    for (int r = 0; r < 4; ++r) {
      Y[(mbase + r) * 512 + col] = acc[j][r] + bv;
    }
  }
}

extern "C" void kernel_launch(void* const* d_in, const int* in_sizes, int n_in,
                              void* d_out, int out_size, void* d_ws, size_t ws_size,
                              hipStream_t stream) {
  const float* x = (const float*)d_in[0];      // [4,2048,512]
  const float* w_qkv = (const float*)d_in[1];  // [1536,512]
  const float* w_out = (const float*)d_in[2];  // [512,512]
  const float* b_out = (const float*)d_in[3];  // [512]
  float* y = (float*)d_out;                    // [4,2048,512] fp32
  char* ws = (char*)d_ws;
  bf16* xb    = (bf16*)(ws);             // 8 MB
  bf16* wqkvb = (bf16*)(ws + 8388608);   // 1.5 MB
  bf16* woutb = (bf16*)(ws + 9961472);   // 0.5 MB
  bf16* Qb    = (bf16*)(ws + 10485760);  // 8 MB  [BH][N][64], prescaled
  bf16* Kb    = (bf16*)(ws + 18874368);  // 8 MB  [BH][N][64]
  bf16* Vt    = (bf16*)(ws + 27262976);  // 8 MB  [BH][64][N]
  bf16* Ob    = (bf16*)(ws + 35651584);  // 8 MB  [B][N][512]

  hipLaunchKernelGGL(cvt_all, dim3(5120), dim3(256), 0, stream, x, w_qkv, w_out, xb);
  hipLaunchKernelGGL(qkv_gemm, dim3(64, 12), dim3(256), 0, stream, xb, wqkvb, Qb, Kb, Vt);
  hipLaunchKernelGGL(attn_fwd, dim3(32, 16), dim3(512), 0, stream, Qb, Kb, Vt, Ob);
  hipLaunchKernelGGL(out_gemm, dim3(128, 8), dim3(256), 0, stream, Ob, woutb, b_out, y);
}

// Round 14
// 80.797 us; speedup vs baseline: 1.0100x; 1.0100x over previous
//
#include <hip/hip_runtime.h>
#include <hip/hip_bf16.h>
#include <stdint.h>

typedef __bf16 bf16;
typedef __bf16 bf16x8 __attribute__((ext_vector_type(8)));
typedef __bf16 bf16x4 __attribute__((ext_vector_type(4)));
typedef float f32x4 __attribute__((ext_vector_type(4)));

template <int V> struct Int { static constexpr int value = V; };

// async global->LDS, 16B per lane. LDS dest must be linear in lane order.
static __device__ __forceinline__ void gl2lds16(const void* g, void* l) {
  const __attribute__((address_space(1))) void* gp =
      reinterpret_cast<const __attribute__((address_space(1))) void*>(
          reinterpret_cast<uintptr_t>(g));
  __attribute__((address_space(3))) void* lp =
      reinterpret_cast<__attribute__((address_space(3))) void*>(
          static_cast<uint32_t>(reinterpret_cast<uintptr_t>(l)));
  __builtin_amdgcn_global_load_lds(gp, lp, 16, 0, 0);
}

// bare v_exp_f32 through the compiler intrinsic (hazard-safe, unlike inline asm).
static __device__ __forceinline__ float fast_exp2(float x) {
#if __has_builtin(__builtin_amdgcn_exp2f)
  return __builtin_amdgcn_exp2f(x);
#else
  return exp2f(x);
#endif
}

// Convert only the weights: w_qkv (786,432 f32) | w_out (262,144 f32) ->
// contiguous bf16 (wqkvb|woutb adjacent). x is consumed as f32 by qkv_gemm now.
__global__ __launch_bounds__(256) void cvt_w(const float* __restrict__ wq,
                                             const float* __restrict__ wo,
                                             bf16* __restrict__ dst) {
  const int i = blockIdx.x * 256 + threadIdx.x;  // grid 1024 -> 262144 float4
  const float4 v = (i < 196608) ? reinterpret_cast<const float4*>(wq)[i]
                                : reinterpret_cast<const float4*>(wo)[i - 196608];
  bf16x4 o;
  o[0] = (bf16)v.x; o[1] = (bf16)v.y; o[2] = (bf16)v.z; o[3] = (bf16)v.w;
  reinterpret_cast<bf16x4*>(dst)[i] = o;
}

// C[m][e] = sum_k X[m][k] * W[e][k];  M=8192, N=1536, K=512.  128x128 tile, BK=32.
// A-operand read DIRECTLY from f32 x (no pre-convert): staged as f32 into a
// XOR-swizzled LDS tile (row byte ^= (row&7)<<4 via pre-swizzled source), read
// as 2x ds_read_b128 per frag and converted to bf16 in-register (cvt_pk).
// LDS: A f32 2x16KB + B bf16 2x8KB = 48KB -> 3 blocks/CU.
// 4 waves, each owns 64x64 (4x4 frags of 16x16x32). Epilogue scatters Q/K/V^T.
__global__ __launch_bounds__(256) void qkv_gemm(const float* __restrict__ X,
                                                const bf16* __restrict__ W,
                                                bf16* __restrict__ Qb,
                                                bf16* __restrict__ Kb,
                                                bf16* __restrict__ Vt) {
  __shared__ __align__(16) float AshF[8192];  // [2][128*32] f32
  __shared__ __align__(16) bf16 BshX[8192];   // [2][128*32] bf16
  const int t = threadIdx.x;
  const int lane = t & 63;
  const int w = t >> 6;
  const int fr = lane & 15, fg = lane >> 4;
  const int wr = w >> 1, wc = w & 1;
  const int m0 = blockIdx.x * 128;
  const int n0 = blockIdx.y * 128;
  // A staging: chunk c (=t+h*256): row=c>>3 (128 rows), seg=c&7 (8x16B per row);
  // source seg ^= row&7 (row&7 == (t>>3)&7 for all h since h*32 is 0 mod 8).
  const float* pA = X + (m0 + (t >> 3)) * 512 + ((t & 7) ^ ((t >> 3) & 7)) * 4;
  // B staging (bf16, unswizzled as before): chunk t -> row t>>2, seg t&3.
  const int r0 = t >> 2, seg = t & 3;
  const bf16* pB0 = W + (n0 + r0) * 512 + seg * 8;
  const bf16* pB1 = W + (n0 + r0 + 64) * 512 + seg * 8;
  // A frag read offsets (swizzled): row = wr*64 + m*16 + fr; sw = (fr&7)<<4.
  const char* af = reinterpret_cast<const char*>(AshF);
  const int koa0 = (wr * 64 + fr) * 128 + (((fg * 2) ^ (fr & 7)) * 16);
  const int koa1 = (wr * 64 + fr) * 128 + (((fg * 2 + 1) ^ (fr & 7)) * 16);
  const bf16* bp = BshX + (wc * 64 + fr) * 32 + fg * 8;

  f32x4 acc[4][4] = {};

  auto stage = [&](auto Bt) {
    constexpr int B = decltype(Bt)::value;
    gl2lds16(pA,         (void*)(AshF + B * 4096 + t * 4));
    gl2lds16(pA + 16384, (void*)(AshF + B * 4096 + 1024 + t * 4));
    gl2lds16(pA + 32768, (void*)(AshF + B * 4096 + 2048 + t * 4));
    gl2lds16(pA + 49152, (void*)(AshF + B * 4096 + 3072 + t * 4));
    gl2lds16(pB0, (void*)(BshX + B * 4096 + t * 8));
    gl2lds16(pB1, (void*)(BshX + B * 4096 + 2048 + t * 8));
    pA += 32; pB0 += 32; pB1 += 32;
  };
  auto step = [&](auto Bt) {
    constexpr int B = decltype(Bt)::value;
    bf16x8 a[4], b[4];
#pragma unroll
    for (int m = 0; m < 4; ++m) {
      const f32x4 a0 = *reinterpret_cast<const f32x4*>(af + B * 16384 + m * 2048 + koa0);
      const f32x4 a1 = *reinterpret_cast<const f32x4*>(af + B * 16384 + m * 2048 + koa1);
#pragma unroll
      for (int i = 0; i < 4; ++i) {
        a[m][i] = (bf16)a0[i];
        a[m][4 + i] = (bf16)a1[i];
      }
    }
#pragma unroll
    for (int n = 0; n < 4; ++n) b[n] = *reinterpret_cast<const bf16x8*>(bp + B * 4096 + n * 512);
#pragma unroll
    for (int m = 0; m < 4; ++m)
#pragma unroll
      for (int n = 0; n < 4; ++n)
        acc[m][n] = __builtin_amdgcn_mfma_f32_16x16x32_bf16(a[m], b[n], acc[m][n], 0, 0, 0);
  };

  stage(Int<0>{});
  __syncthreads();
  for (int kt = 0; kt < 16; kt += 2) {
    stage(Int<1>{});
    step(Int<0>{});
    __syncthreads();
    if (kt < 14) stage(Int<0>{});
    step(Int<1>{});
    __syncthreads();
  }

  // epilogue. C/D: col = lane&15 -> e = n0+wc*64+16n+fr; row = m0+wr*64+16m+fg*4+r
  const int which = n0 >> 9;  // 0=Q 1=K 2=V (uniform per block)
#pragma unroll
  for (int n = 0; n < 4; ++n) {
    const int e = n0 + wc * 64 + 16 * n + fr;
    const int h = (e >> 6) & 7;
    const int d = e & 63;
#pragma unroll
    for (int m = 0; m < 4; ++m) {
      const int mbase = m0 + wr * 64 + 16 * m + fg * 4;
      if (which == 2) {
        bf16x4 pk;
#pragma unroll
        for (int r = 0; r < 4; ++r) pk[r] = (bf16)acc[m][n][r];
        const int b = mbase >> 11, tok = mbase & 2047;
        *reinterpret_cast<bf16x4*>(&Vt[((b * 8 + h) * 64 + d) * 2048 + tok]) = pk;
      } else {
        bf16* dst = (which == 0) ? Qb : Kb;
        const float sc = (which == 0) ? (0.125f * 1.44269504088896f) : 1.0f;
#pragma unroll
        for (int r = 0; r < 4; ++r) {
          const int row = mbase + r;
          const int b = row >> 11, tok = row & 2047;
          dst[((b * 8 + h) * 2048 + tok) * 64 + d] = (bf16)(acc[m][n][r] * sc);
        }
      }
    }
  }
}

// Flash attention, swapped-operand, no-max exp2 softmax, q=32 per wave (r12 best).
// Q [BH][2048][64] (prescaled by 0.125*log2e), K [BH][2048][64], V^T [BH][64][2048].
// Block: 4 waves x 32 q-rows = 128 q. Grid (32 bh, 16 qtile): id == bh (mod 8)
// -> one XCD per head (L2-resident K/V). Lane owns q rows {fr, fr+16}; both
// q-sets share every kf/vf ds_read. K rows PERMUTED at staging so S^T lands in
// PV B-frag layout. 2-slot 32KB LDS dbuf. Split-exp interleave + setprio.
__global__ __launch_bounds__(256, 2) void attn_fwd(const bf16* __restrict__ Qb,
                                                   const bf16* __restrict__ Kb,
                                                   const bf16* __restrict__ Vt,
                                                   bf16* __restrict__ Ob) {
  __shared__ __align__(16) bf16 sh[16384];
  const int t = threadIdx.x;
  const int lane = t & 63;
  const int w = t >> 6;
  const int fr = lane & 15, fg = lane >> 4;
  const int bh = blockIdx.x;
  const int q0 = blockIdx.y * 128 + 32 * w;

  const bf16* Qrow = Qb + (bh * 2048 + q0 + fr) * 64;
  const bf16x8 qa0 = *reinterpret_cast<const bf16x8*>(Qrow + fg * 8);
  const bf16x8 qa1 = *reinterpret_cast<const bf16x8*>(Qrow + 32 + fg * 8);
  const bf16x8 qb0 = *reinterpret_cast<const bf16x8*>(Qrow + 1024 + fg * 8);
  const bf16x8 qb1 = *reinterpret_cast<const bf16x8*>(Qrow + 1024 + 32 + fg * 8);

  bf16x8 ones;
#pragma unroll
  for (int i = 0; i < 8; ++i) ones[i] = (bf16)1.0f;

  const int c0row = t >> 3, cseg = t & 7;
  const int c1row = c0row + 32;
  const int s0 = (cseg ^ (c0row & 7)) * 8;
  const int s1 = (cseg ^ (c1row & 7)) * 8;
  const int kp0 = 32 * ((c0row >> 4) >> 1) + 8 * ((c0row & 15) >> 2) +
                  4 * ((c0row >> 4) & 1) + (c0row & 3);
  const int kp1 = 32 * ((c1row >> 4) >> 1) + 8 * ((c1row & 15) >> 2) +
                  4 * ((c1row >> 4) & 1) + (c1row & 3);
  const bf16* pK0 = Kb + bh * 131072 + kp0 * 64 + s0;
  const bf16* pK1 = Kb + bh * 131072 + kp1 * 64 + s1;
  const bf16* pV0 = Vt + bh * 131072 + c0row * 2048 + s0;
  const bf16* pV1 = Vt + bh * 131072 + c1row * 2048 + s1;

  const int swz = (fr & 7) << 4;
  const int ko0 = fr * 128 + ((fg * 16) ^ swz);
  const int ko1 = fr * 128 + ((64 + fg * 16) ^ swz);
  const char* shb = reinterpret_cast<const char*>(sh);

  f32x4 oA[4] = {}, oB[4] = {};
  f32x4 lA = {}, lB = {};
  const f32x4 fzero = {0.f, 0.f, 0.f, 0.f};

  auto stage = [&](auto St) {
    constexpr int S = decltype(St)::value;
    gl2lds16(pK0, (void*)(sh + S * 4096 + t * 8));
    gl2lds16(pK1, (void*)(sh + S * 4096 + 2048 + t * 8));
    gl2lds16(pV0, (void*)(sh + 8192 + S * 4096 + t * 8));
    gl2lds16(pV1, (void*)(sh + 8192 + S * 4096 + 2048 + t * 8));
    pK0 += 4096; pK1 += 4096; pV0 += 64; pV1 += 64;
  };

  auto compute = [&](auto St) {
    constexpr int S = decltype(St)::value;
    f32x4 sA[4], sB[4];
#pragma unroll
    for (int j = 0; j < 4; ++j) {
      const bf16x8 kf0 = *reinterpret_cast<const bf16x8*>(shb + ko0 + (S * 8192 + j * 2048));
      sA[j] = __builtin_amdgcn_mfma_f32_16x16x32_bf16(kf0, qa0, fzero, 0, 0, 0);
      sB[j] = __builtin_amdgcn_mfma_f32_16x16x32_bf16(kf0, qb0, fzero, 0, 0, 0);
      const bf16x8 kf1 = *reinterpret_cast<const bf16x8*>(shb + ko1 + (S * 8192 + j * 2048));
      sA[j] = __builtin_amdgcn_mfma_f32_16x16x32_bf16(kf1, qa1, sA[j], 0, 0, 0);
      sB[j] = __builtin_amdgcn_mfma_f32_16x16x32_bf16(kf1, qb1, sB[j], 0, 0, 0);
    }
    bf16x8 pA0, pB0;
#pragma unroll
    for (int j = 0; j < 2; ++j)
#pragma unroll
      for (int r = 0; r < 4; ++r) {
        pA0[4 * j + r] = (bf16)fast_exp2(sA[j][r]);
        pB0[4 * j + r] = (bf16)fast_exp2(sB[j][r]);
      }
    __builtin_amdgcn_s_setprio(1);
    lA = __builtin_amdgcn_mfma_f32_16x16x32_bf16(ones, pA0, lA, 0, 0, 0);
    lB = __builtin_amdgcn_mfma_f32_16x16x32_bf16(ones, pB0, lB, 0, 0, 0);
#pragma unroll
    for (int j = 0; j < 4; ++j) {
      const bf16x8 vf = *reinterpret_cast<const bf16x8*>(
          shb + ko0 + (16384 + S * 8192 + j * 2048));
      oA[j] = __builtin_amdgcn_mfma_f32_16x16x32_bf16(vf, pA0, oA[j], 0, 0, 0);
      oB[j] = __builtin_amdgcn_mfma_f32_16x16x32_bf16(vf, pB0, oB[j], 0, 0, 0);
    }
    __builtin_amdgcn_s_setprio(0);
    bf16x8 pA1, pB1;
#pragma unroll
    for (int j = 2; j < 4; ++j)
#pragma unroll
      for (int r = 0; r < 4; ++r) {
        pA1[4 * (j - 2) + r] = (bf16)fast_exp2(sA[j][r]);
        pB1[4 * (j - 2) + r] = (bf16)fast_exp2(sB[j][r]);
      }
    __builtin_amdgcn_s_setprio(1);
    lA = __builtin_amdgcn_mfma_f32_16x16x32_bf16(ones, pA1, lA, 0, 0, 0);
    lB = __builtin_amdgcn_mfma_f32_16x16x32_bf16(ones, pB1, lB, 0, 0, 0);
#pragma unroll
    for (int j = 0; j < 4; ++j) {
      const bf16x8 vf = *reinterpret_cast<const bf16x8*>(
          shb + ko1 + (16384 + S * 8192 + j * 2048));
      oA[j] = __builtin_amdgcn_mfma_f32_16x16x32_bf16(vf, pA1, oA[j], 0, 0, 0);
      oB[j] = __builtin_amdgcn_mfma_f32_16x16x32_bf16(vf, pB1, oB[j], 0, 0, 0);
    }
    __builtin_amdgcn_s_setprio(0);
  };

  stage(Int<0>{});
  __syncthreads();
  for (int kt = 0; kt < 32; kt += 2) {
    stage(Int<1>{});
    compute(Int<0>{});
    __syncthreads();
    if (kt < 30) stage(Int<0>{});
    compute(Int<1>{});
    __syncthreads();
  }

  const int b = bh >> 3, h = bh & 7;
  const int qA = q0 + fr;
  const float invA = 1.0f / lA[0];
  const float invB = 1.0f / lB[0];
#pragma unroll
  for (int j = 0; j < 4; ++j) {
    bf16x4 o4;
#pragma unroll
    for (int r = 0; r < 4; ++r) o4[r] = (bf16)(oA[j][r] * invA);
    *reinterpret_cast<bf16x4*>(&Ob[(b * 2048 + qA) * 512 + h * 64 + 16 * j + 4 * fg]) = o4;
#pragma unroll
    for (int r = 0; r < 4; ++r) o4[r] = (bf16)(oB[j][r] * invB);
    *reinterpret_cast<bf16x4*>(&Ob[(b * 2048 + qA + 16) * 512 + h * 64 + 16 * j + 4 * fg]) = o4;
  }
}

// Y[m][n] = sum_k O[m][k]*W[n][k] + bias[n];  M=8192, N=512, K=512. fp32 out.
// 64x64 tile (r11-proven: 1024 blocks = 4/CU).
__global__ __launch_bounds__(256) void out_gemm(const bf16* __restrict__ O,
                                                const bf16* __restrict__ W,
                                                const float* __restrict__ bias,
                                                float* __restrict__ Y) {
  __shared__ __align__(16) bf16 Ash[2][64 * 32];
  __shared__ __align__(16) bf16 Bsh[2][64 * 32];
  const int t = threadIdx.x;
  const int lane = t & 63;
  const int w = t >> 6;
  const int fr = lane & 15, fg = lane >> 4;
  const int m0 = blockIdx.x * 64;
  const int n0 = blockIdx.y * 64;
  const int srow = t >> 2, sseg = t & 3;
  const bf16* gA = O + (m0 + srow) * 512 + sseg * 8;
  const bf16* gB = W + (n0 + srow) * 512 + sseg * 8;

  f32x4 acc[4] = {};
  gl2lds16(gA, &Ash[0][t * 8]);
  gl2lds16(gB, &Bsh[0][t * 8]);
  __syncthreads();
  int cur = 0;
  for (int kt = 0; kt < 16; ++kt) {
    if (kt < 15) {
      gl2lds16(gA + (kt + 1) * 32, &Ash[cur ^ 1][t * 8]);
      gl2lds16(gB + (kt + 1) * 32, &Bsh[cur ^ 1][t * 8]);
    }
    const bf16x8 a = *reinterpret_cast<const bf16x8*>(&Ash[cur][(16 * w + fr) * 32 + fg * 8]);
#pragma unroll
    for (int j = 0; j < 4; ++j) {
      const bf16x8 b = *reinterpret_cast<const bf16x8*>(&Bsh[cur][(16 * j + fr) * 32 + fg * 8]);
      acc[j] = __builtin_amdgcn_mfma_f32_16x16x32_bf16(a, b, acc[j], 0, 0, 0);
    }
    __syncthreads();
    cur ^= 1;
  }
  const int mbase = m0 + 16 * w + fg * 4;
#pragma unroll
  for (int j = 0; j < 4; ++j) {
    const int col = n0 + 16 * j + fr;
    const float bv = bias[col];
#pragma unroll
    for (int r = 0; r < 4; ++r) {
      Y[(mbase + r) * 512 + col] = acc[j][r] + bv;
    }
  }
}

extern "C" void kernel_launch(void* const* d_in, const int* in_sizes, int n_in,
                              void* d_out, int out_size, void* d_ws, size_t ws_size,
                              hipStream_t stream) {
  const float* x = (const float*)d_in[0];      // [4,2048,512]
  const float* w_qkv = (const float*)d_in[1];  // [1536,512]
  const float* w_out = (const float*)d_in[2];  // [512,512]
  const float* b_out = (const float*)d_in[3];  // [512]
  float* y = (float*)d_out;                    // [4,2048,512] fp32
  char* ws = (char*)d_ws;
  bf16* wqkvb = (bf16*)(ws + 8388608);   // 1.5 MB (x slot at ws+0 now unused)
  bf16* woutb = (bf16*)(ws + 9961472);   // 0.5 MB (contiguous after wqkvb)
  bf16* Qb    = (bf16*)(ws + 10485760);  // 8 MB  [BH][N][64], prescaled
  bf16* Kb    = (bf16*)(ws + 18874368);  // 8 MB  [BH][N][64]
  bf16* Vt    = (bf16*)(ws + 27262976);  // 8 MB  [BH][64][N]
  bf16* Ob    = (bf16*)(ws + 35651584);  // 8 MB  [B][N][512]

  hipLaunchKernelGGL(cvt_w, dim3(1024), dim3(256), 0, stream, w_qkv, w_out, wqkvb);
  hipLaunchKernelGGL(qkv_gemm, dim3(64, 12), dim3(256), 0, stream, x, wqkvb, Qb, Kb, Vt);
  hipLaunchKernelGGL(attn_fwd, dim3(32, 16), dim3(256), 0, stream, Qb, Kb, Vt, Ob);
  hipLaunchKernelGGL(out_gemm, dim3(128, 8), dim3(256), 0, stream, Ob, woutb, b_out, y);
}

// Round 15
// 76.731 us; speedup vs baseline: 1.0635x; 1.0530x over previous
//
#include <hip/hip_runtime.h>
#include <hip/hip_bf16.h>
#include <stdint.h>

typedef __bf16 bf16;
typedef __bf16 bf16x8 __attribute__((ext_vector_type(8)));
typedef __bf16 bf16x4 __attribute__((ext_vector_type(4)));
typedef float f32x4 __attribute__((ext_vector_type(4)));

template <int V> struct Int { static constexpr int value = V; };

// async global->LDS, 16B per lane. LDS dest must be linear in lane order.
static __device__ __forceinline__ void gl2lds16(const void* g, void* l) {
  const __attribute__((address_space(1))) void* gp =
      reinterpret_cast<const __attribute__((address_space(1))) void*>(
          reinterpret_cast<uintptr_t>(g));
  __attribute__((address_space(3))) void* lp =
      reinterpret_cast<__attribute__((address_space(3))) void*>(
          static_cast<uint32_t>(reinterpret_cast<uintptr_t>(l)));
  __builtin_amdgcn_global_load_lds(gp, lp, 16, 0, 0);
}

// bare v_exp_f32 through the compiler intrinsic (hazard-safe, unlike inline asm).
static __device__ __forceinline__ float fast_exp2(float x) {
#if __has_builtin(__builtin_amdgcn_exp2f)
  return __builtin_amdgcn_exp2f(x);
#else
  return exp2f(x);
#endif
}

// One fused convert: x (4,194,304 f32) | w_qkv (786,432) | w_out (262,144) ->
// contiguous bf16 stream in ws (xb|wqkvb|woutb are adjacent).
__global__ __launch_bounds__(256) void cvt_all(const float* __restrict__ x,
                                               const float* __restrict__ wq,
                                               const float* __restrict__ wo,
                                               bf16* __restrict__ dst) {
  int i = blockIdx.x * 256 + threadIdx.x;
  const int stride = gridDim.x * 256;
  for (; i < 1310720; i += stride) {
    const float4 v = (i < 1048576) ? reinterpret_cast<const float4*>(x)[i]
                   : (i < 1245184) ? reinterpret_cast<const float4*>(wq)[i - 1048576]
                                   : reinterpret_cast<const float4*>(wo)[i - 1245184];
    bf16x4 o;
    o[0] = (bf16)v.x; o[1] = (bf16)v.y; o[2] = (bf16)v.z; o[3] = (bf16)v.w;
    reinterpret_cast<bf16x4*>(dst)[i] = o;
  }
}

// C[m][e] = sum_k X[m][k] * W[e][k];  M=8192, N=1536, K=512.  128x128 tile, BK=32.
// 4 waves, each owns 64x64 (4x4 frags of 16x16x32). Epilogue scatters Q/K/V^T.
__global__ __launch_bounds__(256) void qkv_gemm(const bf16* __restrict__ X,
                                                const bf16* __restrict__ W,
                                                bf16* __restrict__ Qb,
                                                bf16* __restrict__ Kb,
                                                bf16* __restrict__ Vt) {
  __shared__ __align__(16) bf16 AshX[8192];  // [2][128*32]
  __shared__ __align__(16) bf16 BshX[8192];
  const int t = threadIdx.x;
  const int lane = t & 63;
  const int w = t >> 6;
  const int fr = lane & 15, fg = lane >> 4;
  const int wr = w >> 1, wc = w & 1;
  const int m0 = blockIdx.x * 128;
  const int n0 = blockIdx.y * 128;
  // staging: chunk t -> row t>>2, seg t&3 -> LDS elem t*8; chunk t+256 -> +2048
  const int r0 = t >> 2, seg = t & 3;
  const bf16* pA0 = X + (m0 + r0) * 512 + seg * 8;
  const bf16* pA1 = X + (m0 + r0 + 64) * 512 + seg * 8;
  const bf16* pB0 = W + (n0 + r0) * 512 + seg * 8;
  const bf16* pB1 = W + (n0 + r0 + 64) * 512 + seg * 8;
  const bf16* ap = AshX + (wr * 64 + fr) * 32 + fg * 8;
  const bf16* bp = BshX + (wc * 64 + fr) * 32 + fg * 8;

  f32x4 acc[4][4] = {};

  auto stage = [&](auto Bt) {
    constexpr int B = decltype(Bt)::value;
    gl2lds16(pA0, (void*)(AshX + B * 4096 + t * 8));
    gl2lds16(pA1, (void*)(AshX + B * 4096 + 2048 + t * 8));
    gl2lds16(pB0, (void*)(BshX + B * 4096 + t * 8));
    gl2lds16(pB1, (void*)(BshX + B * 4096 + 2048 + t * 8));
    pA0 += 32; pA1 += 32; pB0 += 32; pB1 += 32;
  };
  auto step = [&](auto Bt) {
    constexpr int B = decltype(Bt)::value;
    bf16x8 a[4], b[4];
#pragma unroll
    for (int m = 0; m < 4; ++m) a[m] = *reinterpret_cast<const bf16x8*>(ap + B * 4096 + m * 512);
#pragma unroll
    for (int n = 0; n < 4; ++n) b[n] = *reinterpret_cast<const bf16x8*>(bp + B * 4096 + n * 512);
#pragma unroll
    for (int m = 0; m < 4; ++m)
#pragma unroll
      for (int n = 0; n < 4; ++n)
        acc[m][n] = __builtin_amdgcn_mfma_f32_16x16x32_bf16(a[m], b[n], acc[m][n], 0, 0, 0);
  };

  stage(Int<0>{});
  __syncthreads();
  for (int kt = 0; kt < 16; kt += 2) {
    stage(Int<1>{});
    step(Int<0>{});
    __syncthreads();
    if (kt < 14) stage(Int<0>{});
    step(Int<1>{});
    __syncthreads();
  }

  // epilogue. C/D: col = lane&15 -> e = n0+wc*64+16n+fr; row = m0+wr*64+16m+fg*4+r
  const int which = n0 >> 9;  // 0=Q 1=K 2=V (uniform per block)
#pragma unroll
  for (int n = 0; n < 4; ++n) {
    const int e = n0 + wc * 64 + 16 * n + fr;
    const int h = (e >> 6) & 7;
    const int d = e & 63;
#pragma unroll
    for (int m = 0; m < 4; ++m) {
      const int mbase = m0 + wr * 64 + 16 * m + fg * 4;
      if (which == 2) {
        bf16x4 pk;
#pragma unroll
        for (int r = 0; r < 4; ++r) pk[r] = (bf16)acc[m][n][r];
        const int b = mbase >> 11, tok = mbase & 2047;
        *reinterpret_cast<bf16x4*>(&Vt[((b * 8 + h) * 64 + d) * 2048 + tok]) = pk;
      } else {
        bf16* dst = (which == 0) ? Qb : Kb;
        const float sc = (which == 0) ? (0.125f * 1.44269504088896f) : 1.0f;
#pragma unroll
        for (int r = 0; r < 4; ++r) {
          const int row = mbase + r;
          const int b = row >> 11, tok = row & 2047;
          dst[((b * 8 + h) * 2048 + tok) * 64 + d] = (bf16)(acc[m][n][r] * sc);
        }
      }
    }
  }
}

// Flash attention, swapped-operand, no-max exp2 softmax, q=32 per wave.
// Q [BH][2048][64] (prescaled by 0.125*log2e), K [BH][2048][64], V^T [BH][64][2048].
// Block: 4 waves x 32 q-rows = 128 q. Grid (32 bh, 16 qtile): id == bh (mod 8)
// -> one XCD per head (L2-resident K/V). Lane owns q rows {fr, fr+16}; both
// q-sets share every kf/vf ds_read -> HALF the LDS-read bytes per q (the
// saturated pipe per r10 analysis).
// K rows PERMUTED at staging so S^T lands in PV B-frag layout (see r3 header).
// 2-slot 32KB LDS double-buffer. Split-exp: PV half 0 only needs pf*0, so
// pf*1's exp VALU overlaps PV0's MFMAs.
// LDS arena: K slot s @ bytes s*8192, V slot s @ bytes 16384 + s*8192; XOR-swizzled.
__global__ __launch_bounds__(256, 2) void attn_fwd(const bf16* __restrict__ Qb,
                                                   const bf16* __restrict__ Kb,
                                                   const bf16* __restrict__ Vt,
                                                   bf16* __restrict__ Ob) {
  __shared__ __align__(16) bf16 sh[16384];
  const int t = threadIdx.x;
  const int lane = t & 63;
  const int w = t >> 6;
  const int fr = lane & 15, fg = lane >> 4;
  const int bh = blockIdx.x;
  const int q0 = blockIdx.y * 128 + 32 * w;

  // Q fragments (B-operand): col=q, k = 8*fg + i; sets A (q0+fr) and B (q0+16+fr)
  const bf16* Qrow = Qb + (bh * 2048 + q0 + fr) * 64;
  const bf16x8 qa0 = *reinterpret_cast<const bf16x8*>(Qrow + fg * 8);
  const bf16x8 qa1 = *reinterpret_cast<const bf16x8*>(Qrow + 32 + fg * 8);
  const bf16x8 qb0 = *reinterpret_cast<const bf16x8*>(Qrow + 1024 + fg * 8);
  const bf16x8 qb1 = *reinterpret_cast<const bf16x8*>(Qrow + 1024 + 32 + fg * 8);

  bf16x8 ones;
#pragma unroll
  for (int i = 0; i < 8; ++i) ones[i] = (bf16)1.0f;

  // staging: chunk c: LDS row=c>>3, seg=c&7; src seg ^= (dstrow&7); K row-permuted.
  const int c0row = t >> 3, cseg = t & 7;
  const int c1row = c0row + 32;
  const int s0 = (cseg ^ (c0row & 7)) * 8;
  const int s1 = (cseg ^ (c1row & 7)) * 8;
  const int kp0 = 32 * ((c0row >> 4) >> 1) + 8 * ((c0row & 15) >> 2) +
                  4 * ((c0row >> 4) & 1) + (c0row & 3);
  const int kp1 = 32 * ((c1row >> 4) >> 1) + 8 * ((c1row & 15) >> 2) +
                  4 * ((c1row >> 4) & 1) + (c1row & 3);
  const bf16* pK0 = Kb + bh * 131072 + kp0 * 64 + s0;
  const bf16* pK1 = Kb + bh * 131072 + kp1 * 64 + s1;
  const bf16* pV0 = Vt + bh * 131072 + c0row * 2048 + s0;
  const bf16* pV1 = Vt + bh * 131072 + c1row * 2048 + s1;

  // LDS read byte offsets (2 VGPRs; everything else is an immediate)
  const int swz = (fr & 7) << 4;
  const int ko0 = fr * 128 + ((fg * 16) ^ swz);
  const int ko1 = fr * 128 + ((64 + fg * 16) ^ swz);
  const char* shb = reinterpret_cast<const char*>(sh);

  f32x4 oA[4] = {}, oB[4] = {};
  f32x4 lA = {}, lB = {};
  const f32x4 fzero = {0.f, 0.f, 0.f, 0.f};

  auto stage = [&](auto St) {
    constexpr int S = decltype(St)::value;
    gl2lds16(pK0, (void*)(sh + S * 4096 + t * 8));
    gl2lds16(pK1, (void*)(sh + S * 4096 + 2048 + t * 8));
    gl2lds16(pV0, (void*)(sh + 8192 + S * 4096 + t * 8));
    gl2lds16(pV1, (void*)(sh + 8192 + S * 4096 + 2048 + t * 8));
    pK0 += 4096; pK1 += 4096; pV0 += 64; pV1 += 64;
  };

  auto compute = [&](auto St) {
    constexpr int S = decltype(St)::value;
    f32x4 sA[4], sB[4];
#pragma unroll
    for (int j = 0; j < 4; ++j) {
      const bf16x8 kf0 = *reinterpret_cast<const bf16x8*>(shb + ko0 + (S * 8192 + j * 2048));
      sA[j] = __builtin_amdgcn_mfma_f32_16x16x32_bf16(kf0, qa0, fzero, 0, 0, 0);
      sB[j] = __builtin_amdgcn_mfma_f32_16x16x32_bf16(kf0, qb0, fzero, 0, 0, 0);
      const bf16x8 kf1 = *reinterpret_cast<const bf16x8*>(shb + ko1 + (S * 8192 + j * 2048));
      sA[j] = __builtin_amdgcn_mfma_f32_16x16x32_bf16(kf1, qa1, sA[j], 0, 0, 0);
      sB[j] = __builtin_amdgcn_mfma_f32_16x16x32_bf16(kf1, qb1, sB[j], 0, 0, 0);
    }
    // half 0: exp for j=0,1 of both q-sets; PV half 0 only needs these
    bf16x8 pA0, pB0;
#pragma unroll
    for (int j = 0; j < 2; ++j)
#pragma unroll
      for (int r = 0; r < 4; ++r) {
        pA0[4 * j + r] = (bf16)fast_exp2(sA[j][r]);
        pB0[4 * j + r] = (bf16)fast_exp2(sB[j][r]);
      }
    __builtin_amdgcn_s_setprio(1);
    lA = __builtin_amdgcn_mfma_f32_16x16x32_bf16(ones, pA0, lA, 0, 0, 0);
    lB = __builtin_amdgcn_mfma_f32_16x16x32_bf16(ones, pB0, lB, 0, 0, 0);
#pragma unroll
    for (int j = 0; j < 4; ++j) {
      const bf16x8 vf = *reinterpret_cast<const bf16x8*>(
          shb + ko0 + (16384 + S * 8192 + j * 2048));
      oA[j] = __builtin_amdgcn_mfma_f32_16x16x32_bf16(vf, pA0, oA[j], 0, 0, 0);
      oB[j] = __builtin_amdgcn_mfma_f32_16x16x32_bf16(vf, pB0, oB[j], 0, 0, 0);
    }
    __builtin_amdgcn_s_setprio(0);
    // half 1
    bf16x8 pA1, pB1;
#pragma unroll
    for (int j = 2; j < 4; ++j)
#pragma unroll
      for (int r = 0; r < 4; ++r) {
        pA1[4 * (j - 2) + r] = (bf16)fast_exp2(sA[j][r]);
        pB1[4 * (j - 2) + r] = (bf16)fast_exp2(sB[j][r]);
      }
    __builtin_amdgcn_s_setprio(1);
    lA = __builtin_amdgcn_mfma_f32_16x16x32_bf16(ones, pA1, lA, 0, 0, 0);
    lB = __builtin_amdgcn_mfma_f32_16x16x32_bf16(ones, pB1, lB, 0, 0, 0);
#pragma unroll
    for (int j = 0; j < 4; ++j) {
      const bf16x8 vf = *reinterpret_cast<const bf16x8*>(
          shb + ko1 + (16384 + S * 8192 + j * 2048));
      oA[j] = __builtin_amdgcn_mfma_f32_16x16x32_bf16(vf, pA1, oA[j], 0, 0, 0);
      oB[j] = __builtin_amdgcn_mfma_f32_16x16x32_bf16(vf, pB1, oB[j], 0, 0, 0);
    }
    __builtin_amdgcn_s_setprio(0);
  };

  stage(Int<0>{});
  __syncthreads();
  for (int kt = 0; kt < 32; kt += 2) {
    stage(Int<1>{});
    compute(Int<0>{});
    __syncthreads();
    if (kt < 30) stage(Int<0>{});
    compute(Int<1>{});
    __syncthreads();
  }

  // epilogue: oX[j][r] = O[q][d=16j+4fg+r]; l = lX[0] (all slots equal)
  const int b = bh >> 3, h = bh & 7;
  const int qA = q0 + fr;
  const float invA = 1.0f / lA[0];
  const float invB = 1.0f / lB[0];
#pragma unroll
  for (int j = 0; j < 4; ++j) {
    bf16x4 o4;
#pragma unroll
    for (int r = 0; r < 4; ++r) o4[r] = (bf16)(oA[j][r] * invA);
    *reinterpret_cast<bf16x4*>(&Ob[(b * 2048 + qA) * 512 + h * 64 + 16 * j + 4 * fg]) = o4;
#pragma unroll
    for (int r = 0; r < 4; ++r) o4[r] = (bf16)(oB[j][r] * invB);
    *reinterpret_cast<bf16x4*>(&Ob[(b * 2048 + qA + 16) * 512 + h * 64 + 16 * j + 4 * fg]) = o4;
  }
}

// Y[m][n] = sum_k O[m][k]*W[n][k] + bias[n];  M=8192, N=512, K=512. fp32 out.
// 64x64 tile (proven best: 1024 blocks = 4/CU; 128^2 at 1 block/CU regressed).
__global__ __launch_bounds__(256) void out_gemm(const bf16* __restrict__ O,
                                                const bf16* __restrict__ W,
                                                const float* __restrict__ bias,
                                                float* __restrict__ Y) {
  __shared__ __align__(16) bf16 Ash[2][64 * 32];
  __shared__ __align__(16) bf16 Bsh[2][64 * 32];
  const int t = threadIdx.x;
  const int lane = t & 63;
  const int w = t >> 6;
  const int fr = lane & 15, fg = lane >> 4;
  const int m0 = blockIdx.x * 64;
  const int n0 = blockIdx.y * 64;
  const int srow = t >> 2, sseg = t & 3;
  const bf16* gA = O + (m0 + srow) * 512 + sseg * 8;
  const bf16* gB = W + (n0 + srow) * 512 + sseg * 8;

  f32x4 acc[4] = {};
  gl2lds16(gA, &Ash[0][t * 8]);
  gl2lds16(gB, &Bsh[0][t * 8]);
  __syncthreads();
  int cur = 0;
  for (int kt = 0; kt < 16; ++kt) {
    if (kt < 15) {
      gl2lds16(gA + (kt + 1) * 32, &Ash[cur ^ 1][t * 8]);
      gl2lds16(gB + (kt + 1) * 32, &Bsh[cur ^ 1][t * 8]);
    }
    const bf16x8 a = *reinterpret_cast<const bf16x8*>(&Ash[cur][(16 * w + fr) * 32 + fg * 8]);
#pragma unroll
    for (int j = 0; j < 4; ++j) {
      const bf16x8 b = *reinterpret_cast<const bf16x8*>(&Bsh[cur][(16 * j + fr) * 32 + fg * 8]);
      acc[j] = __builtin_amdgcn_mfma_f32_16x16x32_bf16(a, b, acc[j], 0, 0, 0);
    }
    __syncthreads();
    cur ^= 1;
  }
  const int mbase = m0 + 16 * w + fg * 4;
#pragma unroll
  for (int j = 0; j < 4; ++j) {
    const int col = n0 + 16 * j + fr;
    const float bv = bias[col];
#pragma unroll
    for (int r = 0; r < 4; ++r) {
      Y[(mbase + r) * 512 + col] = acc[j][r] + bv;
    }
  }
}

extern "C" void kernel_launch(void* const* d_in, const int* in_sizes, int n_in,
                              void* d_out, int out_size, void* d_ws, size_t ws_size,
                              hipStream_t stream) {
  const float* x = (const float*)d_in[0];      // [4,2048,512]
  const float* w_qkv = (const float*)d_in[1];  // [1536,512]
  const float* w_out = (const float*)d_in[2];  // [512,512]
  const float* b_out = (const float*)d_in[3];  // [512]
  float* y = (float*)d_out;                    // [4,2048,512] fp32
  char* ws = (char*)d_ws;
  bf16* xb    = (bf16*)(ws);             // 8 MB
  bf16* wqkvb = (bf16*)(ws + 8388608);   // 1.5 MB
  bf16* woutb = (bf16*)(ws + 9961472);   // 0.5 MB
  bf16* Qb    = (bf16*)(ws + 10485760);  // 8 MB  [BH][N][64], prescaled
  bf16* Kb    = (bf16*)(ws + 18874368);  // 8 MB  [BH][N][64]
  bf16* Vt    = (bf16*)(ws + 27262976);  // 8 MB  [BH][64][N]
  bf16* Ob    = (bf16*)(ws + 35651584);  // 8 MB  [B][N][512]

  hipLaunchKernelGGL(cvt_all, dim3(5120), dim3(256), 0, stream, x, w_qkv, w_out, xb);
  hipLaunchKernelGGL(qkv_gemm, dim3(64, 12), dim3(256), 0, stream, xb, wqkvb, Qb, Kb, Vt);
  hipLaunchKernelGGL(attn_fwd, dim3(32, 16), dim3(256), 0, stream, Qb, Kb, Vt, Ob);
  hipLaunchKernelGGL(out_gemm, dim3(128, 8), dim3(256), 0, stream, Ob, woutb, b_out, y);
}